// Round 5
// baseline (587.878 us; speedup 1.0000x reference)
//
#include <hip/hip_runtime.h>
#include <cstdint>
#include <cstddef>

#define B_ 64
#define S_ 2048
#define H_ 512
#define R_ 256
#define M_ (B_ * S_)   // 131072
#define NEGV (-1.0e9f)

typedef short short8 __attribute__((ext_vector_type(8)));
typedef unsigned short u16x8 __attribute__((ext_vector_type(8)));
typedef float f32x4 __attribute__((ext_vector_type(4)));
typedef unsigned short u16;

// ---------- helpers ----------
__device__ __forceinline__ u16 f2b(float x) {
    union { float f; uint32_t u; } c; c.f = x;
    uint32_t u = c.u;
    uint32_t r = (u + 0x7fffu + ((u >> 16) & 1u)) >> 16;   // RNE
    return (u16)r;
}
__device__ __forceinline__ float b2f(u16 u) {
    union { uint32_t u; float f; } c; c.u = ((uint32_t)u) << 16;
    return c.f;
}
// HW packed f32->bf16 (RNE, identical result to f2b): dst.lo=cvt(lo), dst.hi=cvt(hi)
__device__ __forceinline__ uint32_t pk2(float lo, float hi) {
    uint32_t r;
    asm("v_cvt_pk_bf16_f32 %0, %1, %2" : "=v"(r) : "v"(lo), "v"(hi));
    return r;
}

// ---------- K1: base[b,k] = rel@Wr^T + Wr_b + pool@Wg^T + Wg_b + Wh_b  (+ Wh_w f32->bf16) ----------
__global__ void k_base(const float* __restrict__ rel, const float* __restrict__ pool,
                       const float* __restrict__ Wg_w, const float* __restrict__ Wg_b,
                       const float* __restrict__ Wh_b,
                       const float* __restrict__ Wr_w, const float* __restrict__ Wr_b,
                       const float* __restrict__ whw, float* __restrict__ base,
                       u16* __restrict__ whwb) {
    int tid = threadIdx.x;
    {   // convert Wh_w: 262144 elems = 65536 float4 groups; exactly one per thread
        int gi = blockIdx.x * 256 + tid;
        float4 v = ((const float4*)whw)[gi];
        ushort4 o; o.x = f2b(v.x); o.y = f2b(v.y); o.z = f2b(v.z); o.w = f2b(v.w);
        ((ushort4*)whwb)[gi] = o;
    }
    int b = blockIdx.x >> 2, q = blockIdx.x & 3;
    __shared__ __attribute__((aligned(16))) float srel[R_];
    __shared__ __attribute__((aligned(16))) float spool[H_];
    __shared__ float accs[128];
    srel[tid & 255] = rel[b * R_ + (tid & 255)];
    for (int i = tid; i < H_; i += 256) spool[i] = pool[b * H_ + i];
    __syncthreads();
    int kk = tid & 127, half = tid >> 7;
    int k = q * 128 + kk;
    float acc = 0.f;
    if (half == 0) {
        acc = Wr_b[k] + Wg_b[k] + Wh_b[k];
        const float4* wr = (const float4*)(Wr_w + (size_t)k * R_);
        #pragma unroll 8
        for (int r4 = 0; r4 < R_ / 4; ++r4) {
            float4 w = wr[r4]; float4 x = ((const float4*)srel)[r4];
            acc += w.x * x.x + w.y * x.y + w.z * x.z + w.w * x.w;
        }
        const float4* wg = (const float4*)(Wg_w + (size_t)k * H_);
        #pragma unroll 8
        for (int h4 = 0; h4 < 32; ++h4) {
            float4 w = wg[h4]; float4 x = ((const float4*)spool)[h4];
            acc += w.x * x.x + w.y * x.y + w.z * x.z + w.w * x.w;
        }
    } else {
        const float4* wg = (const float4*)(Wg_w + (size_t)k * H_);
        #pragma unroll 8
        for (int h4 = 32; h4 < 128; ++h4) {
            float4 w = wg[h4]; float4 x = ((const float4*)spool)[h4];
            acc += w.x * x.x + w.y * x.y + w.z * x.z + w.w * x.w;
        }
    }
    if (half) accs[kk] = acc;
    __syncthreads();
    if (!half) base[b * H_ + k] = acc + accs[kk];
}

// ---------- K2: main GEMM [M,512]x[512,512]^T + tanh/alpha epilogue -> partial[4][M] ----------
// v5: deep register pipeline, NO vmcnt at barriers.
//  - B (Wh_w, L2-resident) is loaded register-direct per-lane-fragment, TWO iterations
//    ahead (bv[2] slots) -- never touches LDS. Round-3's mapping (verified), but with a
//    ~1.7-iteration load->use window instead of zero.
//  - A (sent_h f32) is loaded to regs one iteration ahead, cvt_pk'd to bf16 and
//    ds_write'n to smA[nxt] AFTER the MFMA phase (full-iteration window).
//  - Barriers are raw s_barrier + lgkmcnt(0): LDS consistency needs only ds-op ordering;
//    all global-load waits are compiler-inserted register dependencies. The VM queue is
//    NEVER force-drained (kills round-4's per-step vmcnt(0) stall).
__launch_bounds__(256)
__global__ void k_gemm(const float* __restrict__ A32,  // [M, 512] f32 (sent_h)
                       const u16* __restrict__ Bw,     // [512, 512] bf16 (Wh_w, B^T layout)
                       const float* __restrict__ base,  // [B_, H_]
                       const float* __restrict__ alpha, // [H_]
                       float* __restrict__ partial)     // [4][M]
{
    const int K = 512;
    int j = blockIdx.x;
    int xcd  = j & 7;
    int slot0 = j >> 3;
    int nb   = slot0 & 3;
    int mb   = (slot0 >> 2) * 8 + xcd;   // 0..1023, bijective over grid 4096
    int m0 = mb * 128;
    int n0 = nb * 128;
    int b  = m0 >> 11;   // m0 / S_

    int tid = threadIdx.x;
    int w  = tid >> 6;      // wave 0..3
    int l  = tid & 63;
    int wm = w & 1, wn = w >> 1;
    int lr = l & 15;        // C col / frag row
    int lq = l >> 4;        // quad

    __shared__ __attribute__((aligned(16))) u16 smA[2][128 * 64];   // 2 x 16 KB
    __shared__ float red[2][2][64];

    f32x4 zero = {0.f, 0.f, 0.f, 0.f};
    f32x4 acc[4][4];
    #pragma unroll
    for (int i = 0; i < 4; ++i)
        #pragma unroll
        for (int jj = 0; jj < 4; ++jj) acc[i][jj] = zero;

    // A chunk geometry (chunk c = w*4+i): row=(c>>1)*16+lr, colgroup=(c&1)*32+lq*8
    const float4* gA[4];
    #pragma unroll
    for (int i = 0; i < 4; ++i) {
        int c = w * 4 + i;
        gA[i] = (const float4*)(A32 + (size_t)(m0 + (c >> 1) * 16 + lr) * K + (c & 1) * 32 + lq * 8);
    }
    // B fragment geometry: row n0+wn*64+ni*16+lr, cols kt*64 + kc*32 + lq*8 (.. +8)
    const short8* gB[4];
    #pragma unroll
    for (int ni = 0; ni < 4; ++ni)
        gB[ni] = (const short8*)(Bw + (size_t)(n0 + wn * 64 + ni * 16 + lr) * K + lq * 8);

    float4 av[2][4][2];    // 2-slot A pipeline (f32 in flight), 64 VGPR
    short8 bv[2][2][4];    // 2-slot B pipeline [slot][kc][ni], 64 VGPR

    auto LOAD_A = [&](int slot, int kt) {
        #pragma unroll
        for (int i = 0; i < 4; ++i) {
            av[slot][i][0] = gA[i][kt * 16];
            av[slot][i][1] = gA[i][kt * 16 + 1];
        }
    };
    auto LOAD_B = [&](int slot, int kt) {
        #pragma unroll
        for (int kc = 0; kc < 2; ++kc)
            #pragma unroll
            for (int ni = 0; ni < 4; ++ni)
                bv[slot][kc][ni] = gB[ni][kt * 8 + kc * 4];
    };
    auto WRITE_A = [&](int buf, int slot) {   // cvt + deposit (compiler waits the av loads)
        #pragma unroll
        for (int i = 0; i < 4; ++i) {
            uint4 pv;
            pv.x = pk2(av[slot][i][0].x, av[slot][i][0].y);
            pv.y = pk2(av[slot][i][0].z, av[slot][i][0].w);
            pv.z = pk2(av[slot][i][1].x, av[slot][i][1].y);
            pv.w = pk2(av[slot][i][1].z, av[slot][i][1].w);
            *(uint4*)(smA[buf] + (w * 4 + i) * 512 + l * 8) = pv;
        }
    };

    // prologue: fill 2-deep pipeline, stage smA[0]
    LOAD_A(0, 0); LOAD_B(0, 0);
    LOAD_A(1, 1); LOAD_B(1, 1);
    WRITE_A(0, 0);     // A(0) -> smA[0]

    #pragma unroll
    for (int kt = 0; kt < 8; ++kt) {
        const int cur = kt & 1, nxt = cur ^ 1, slot = kt & 1;
        // flush own ds_writes, sync; NO vm drain
        asm volatile("s_waitcnt lgkmcnt(0)" ::: "memory");
        __builtin_amdgcn_s_barrier();
        __builtin_amdgcn_sched_barrier(0);
        // compute on smA[cur] x bv[slot] (B(kt), loaded 2 iters ago)
        __builtin_amdgcn_s_setprio(1);
        #pragma unroll
        for (int kc = 0; kc < 2; ++kc) {
            short8 af[4];
            #pragma unroll
            for (int mi = 0; mi < 4; ++mi)
                af[mi] = *(const short8*)(smA[cur] + ((wm * 4 + mi) * 2 + kc) * 512 + l * 8);
            #pragma unroll
            for (int mi = 0; mi < 4; ++mi)
                #pragma unroll
                for (int ni = 0; ni < 4; ++ni)
                    acc[mi][ni] = __builtin_amdgcn_mfma_f32_16x16x32_bf16(af[mi], bv[slot][kc][ni], acc[mi][ni], 0, 0, 0);
        }
        __builtin_amdgcn_s_setprio(0);
        // refill pipeline 2 ahead (slots just freed), then deposit A(kt+1) into smA[nxt]
        if (kt < 6) { LOAD_A(slot, kt + 2); LOAD_B(slot, kt + 2); }
        if (kt < 7) WRITE_A(nxt, (kt + 1) & 1);
    }

    // epilogue: sum_n tanh(acc + base[b,n]) * alpha[n] = sum(a) - sum 2a/(exp2(C2*v)+1)
    const float C2 = 2.8853900817779268f;   // 2*log2(e)
    float base2[4], a2[4];
    float asum = 0.f;
    #pragma unroll
    for (int ni = 0; ni < 4; ++ni) {
        int n = n0 + wn * 64 + ni * 16 + lr;
        base2[ni] = C2 * base[b * H_ + n];
        float al  = alpha[n];
        a2[ni] = 2.0f * al;
        asum  += al;
    }
    __syncthreads();   // safe full sync before red[] reuse patterns (epilogue only, once)
    #pragma unroll
    for (int mi = 0; mi < 4; ++mi) {
        #pragma unroll
        for (int r = 0; r < 4; ++r) {
            float s = asum;
            #pragma unroll
            for (int ni = 0; ni < 4; ++ni) {
                float f  = fmaf(acc[mi][ni][r], C2, base2[ni]);
                float e  = __builtin_amdgcn_exp2f(f);
                float rr = __builtin_amdgcn_rcpf(e + 1.0f);
                s = fmaf(-a2[ni], rr, s);
            }
            s += __shfl_xor(s, 1);
            s += __shfl_xor(s, 2);
            s += __shfl_xor(s, 4);
            s += __shfl_xor(s, 8);
            if (lr == 0) red[wm][wn][mi * 16 + lq * 4 + r] = s;
        }
    }
    __syncthreads();
    if (tid < 128) {
        int wmi = tid >> 6, row = tid & 63;
        float sum = red[wmi][0][row] + red[wmi][1][row];
        partial[(size_t)nb * M_ + m0 + wmi * 64 + row] = sum;
    }
}

// ---------- K3: softmax over S per b ----------
__global__ void k_softmax(const float* __restrict__ partial, const int* __restrict__ mask,
                          const float* __restrict__ alpha_b, float* __restrict__ wout) {
    int b = blockIdx.x;
    int tid = threadIdx.x;
    __shared__ float sred[8];
    float x[8];
    float ab = alpha_b[0];
    float lmax = -3.0e38f;
    #pragma unroll
    for (int jj = 0; jj < 8; ++jj) {
        int s = tid + jj * 256;
        size_t m = (size_t)b * S_ + s;
        float v = partial[m] + partial[(size_t)M_ + m] + partial[2 * (size_t)M_ + m] + partial[3 * (size_t)M_ + m] + ab;
        if (mask[b * S_ + s] == 0) v = NEGV;
        x[jj] = v;
        lmax = fmaxf(lmax, v);
    }
    #pragma unroll
    for (int off = 1; off < 64; off <<= 1) lmax = fmaxf(lmax, __shfl_xor(lmax, off));
    int wv = tid >> 6, l = tid & 63;
    if (l == 0) sred[wv] = lmax;
    __syncthreads();
    float gmax = fmaxf(fmaxf(sred[0], sred[1]), fmaxf(sred[2], sred[3]));
    float lsum = 0.f;
    #pragma unroll
    for (int jj = 0; jj < 8; ++jj) { x[jj] = __expf(x[jj] - gmax); lsum += x[jj]; }
    #pragma unroll
    for (int off = 1; off < 64; off <<= 1) lsum += __shfl_xor(lsum, off);
    if (l == 0) sred[4 + wv] = lsum;
    __syncthreads();
    float inv = 1.f / (sred[4] + sred[5] + sred[6] + sred[7]);
    #pragma unroll
    for (int jj = 0; jj < 8; ++jj) {
        int s = tid + jj * 256;
        wout[(size_t)b * S_ + s] = x[jj] * inv;
    }
}

// ---------- K4: t[b,h'] = sum_s w[b,s] * sent_h[b,s,h']  (f32 source) ----------
__global__ void k_wsum(const float* __restrict__ sent, const float* __restrict__ wrow_g,
                       float* __restrict__ t) {
    int b  = blockIdx.x >> 3;
    int hc = blockIdx.x & 7;
    int tid = threadIdx.x;
    __shared__ __attribute__((aligned(16))) float wrow[S_];   // 8 KB
    __shared__ float red[64][33];                             // 8.4 KB, padded
    ((float4*)wrow)[tid]       = ((const float4*)(wrow_g + (size_t)b * S_))[tid];
    ((float4*)wrow)[tid + 256] = ((const float4*)(wrow_g + (size_t)b * S_))[tid + 256];
    __syncthreads();
    int hi = tid & 7;          // 8 col-groups x 8 cols = 64 cols
    int sg = tid >> 3;         // 32 s-groups
    const float* bp = sent + (size_t)b * S_ * H_ + hc * 64 + hi * 8;
    float acc[8] = {0.f, 0.f, 0.f, 0.f, 0.f, 0.f, 0.f, 0.f};
    for (int sb = 0; sb < S_; sb += 256) {
        float4 v[8][2];
        #pragma unroll
        for (int u = 0; u < 8; ++u) {
            const float4* p = (const float4*)(bp + (size_t)(sb + sg + u * 32) * H_);
            v[u][0] = p[0]; v[u][1] = p[1];
        }
        #pragma unroll
        for (int u = 0; u < 8; ++u) {
            float wgt = wrow[sb + sg + u * 32];
            acc[0] = fmaf(wgt, v[u][0].x, acc[0]);
            acc[1] = fmaf(wgt, v[u][0].y, acc[1]);
            acc[2] = fmaf(wgt, v[u][0].z, acc[2]);
            acc[3] = fmaf(wgt, v[u][0].w, acc[3]);
            acc[4] = fmaf(wgt, v[u][1].x, acc[4]);
            acc[5] = fmaf(wgt, v[u][1].y, acc[5]);
            acc[6] = fmaf(wgt, v[u][1].z, acc[6]);
            acc[7] = fmaf(wgt, v[u][1].w, acc[7]);
        }
    }
    #pragma unroll
    for (int e = 0; e < 8; ++e) red[hi * 8 + e][sg] = acc[e];
    __syncthreads();
    if (tid < 64) {
        float s = 0.f;
        #pragma unroll
        for (int g = 0; g < 32; ++g) s += red[tid][g];
        t[(size_t)b * H_ + hc * 64 + tid] = s;
    }
}

// ---------- K5: att_res[b,h] = Wh_b[h] + sum_h' t[b,h'] * Wh_w[h,h']  (grid 256) ----------
__global__ void k_att(const float* __restrict__ t, const float* __restrict__ Whw,
                      const float* __restrict__ Whb, float* __restrict__ out) {
    int tid = threadIdx.x;
    int b = blockIdx.x >> 2, q = blockIdx.x & 3;
    __shared__ __attribute__((aligned(16))) float st[H_];
    __shared__ float accs[128];
    for (int i = tid; i < H_; i += 256) st[i] = t[(size_t)b * H_ + i];
    __syncthreads();
    int hh = tid & 127, half = tid >> 7;
    int h = q * 128 + hh;
    const float4* wr = (const float4*)(Whw + (size_t)h * H_) + half * 64;
    const float4* sx = (const float4*)st + half * 64;
    float acc = 0.f;
    #pragma unroll 8
    for (int i = 0; i < 64; ++i) {
        float4 w = wr[i]; float4 x = sx[i];
        acc += w.x * x.x + w.y * x.y + w.z * x.z + w.w * x.w;
    }
    if (half) accs[hh] = acc;
    __syncthreads();
    if (!half) out[(size_t)b * H_ + h] = acc + accs[hh] + Whb[h];
}

extern "C" void kernel_launch(void* const* d_in, const int* in_sizes, int n_in,
                              void* d_out, int out_size, void* d_ws, size_t ws_size,
                              hipStream_t stream) {
    const float* sent_h  = (const float*)d_in[0];
    const float* rel     = (const float*)d_in[1];
    const float* pool    = (const float*)d_in[2];
    const int*   mask    = (const int*)d_in[3];
    const float* Wg_w    = (const float*)d_in[4];
    const float* Wg_b    = (const float*)d_in[5];
    const float* Wh_w    = (const float*)d_in[6];
    const float* Wh_b    = (const float*)d_in[7];
    const float* Wr_w    = (const float*)d_in[8];
    const float* Wr_b    = (const float*)d_in[9];
    const float* alpha_w = (const float*)d_in[10];
    const float* alpha_b = (const float*)d_in[11];
    float* out = (float*)d_out;

    char* ws = (char*)d_ws;
    u16*   whwb    = (u16*)ws;                       // 524288 B
    float* base    = (float*)(ws + 524288);          // 131072 B
    float* partial = (float*)(ws + 524288 + 131072); // 2097152 B
    float* tbuf    = (float*)(ws + 524288 + 131072 + 2097152); // 131072 B

    float* att_out = out;             // [64,512]
    float* w_out   = out + B_ * H_;   // [64,2048]

    k_base<<<dim3(256), dim3(256), 0, stream>>>(rel, pool, Wg_w, Wg_b, Wh_b, Wr_w, Wr_b, Wh_w, base, whwb);
    k_gemm<<<dim3((M_ / 128) * 4), dim3(256), 0, stream>>>(sent_h, whwb, base, alpha_w, partial);
    k_softmax<<<dim3(B_), dim3(256), 0, stream>>>(partial, mask, alpha_b, w_out);
    k_wsum<<<dim3(B_ * 8), dim3(256), 0, stream>>>(sent_h, w_out, tbuf);
    k_att<<<dim3(256), dim3(256), 0, stream>>>(tbuf, Wh_w, Wh_b, att_out);
}

// Round 6
// 572.456 us; speedup vs baseline: 1.0269x; 1.0269x over previous
//
#include <hip/hip_runtime.h>
#include <cstdint>
#include <cstddef>

#define B_ 64
#define S_ 2048
#define H_ 512
#define R_ 256
#define M_ (B_ * S_)   // 131072
#define NEGV (-1.0e9f)

typedef short short8 __attribute__((ext_vector_type(8)));
typedef unsigned short u16x8 __attribute__((ext_vector_type(8)));
typedef float f32x4 __attribute__((ext_vector_type(4)));
typedef unsigned short u16;

// ---------- helpers ----------
__device__ __forceinline__ u16 f2b(float x) {
    union { float f; uint32_t u; } c; c.f = x;
    uint32_t u = c.u;
    uint32_t r = (u + 0x7fffu + ((u >> 16) & 1u)) >> 16;   // RNE
    return (u16)r;
}
__device__ __forceinline__ float b2f(u16 u) {
    union { uint32_t u; float f; } c; c.u = ((uint32_t)u) << 16;
    return c.f;
}
// HW packed f32->bf16 (RNE, identical result to f2b): dst.lo=cvt(lo), dst.hi=cvt(hi)
__device__ __forceinline__ uint32_t pk2(float lo, float hi) {
    uint32_t r;
    asm("v_cvt_pk_bf16_f32 %0, %1, %2" : "=v"(r) : "v"(lo), "v"(hi));
    return r;
}
__device__ __forceinline__ void load_lds16(const void* g, void* l) {
    __builtin_amdgcn_global_load_lds((__attribute__((address_space(1))) void*)g,
                                     (__attribute__((address_space(3))) void*)l,
                                     16, 0, 0);
}

// ---------- K1: base[b,k] = rel@Wr^T + Wr_b + pool@Wg^T + Wg_b + Wh_b  (+ Wh_w f32->bf16) ----------
__global__ void k_base(const float* __restrict__ rel, const float* __restrict__ pool,
                       const float* __restrict__ Wg_w, const float* __restrict__ Wg_b,
                       const float* __restrict__ Wh_b,
                       const float* __restrict__ Wr_w, const float* __restrict__ Wr_b,
                       const float* __restrict__ whw, float* __restrict__ base,
                       u16* __restrict__ whwb) {
    int tid = threadIdx.x;
    {   // convert Wh_w: 262144 elems = 65536 float4 groups; exactly one per thread
        int gi = blockIdx.x * 256 + tid;
        float4 v = ((const float4*)whw)[gi];
        ushort4 o; o.x = f2b(v.x); o.y = f2b(v.y); o.z = f2b(v.z); o.w = f2b(v.w);
        ((ushort4*)whwb)[gi] = o;
    }
    int b = blockIdx.x >> 2, q = blockIdx.x & 3;
    __shared__ __attribute__((aligned(16))) float srel[R_];
    __shared__ __attribute__((aligned(16))) float spool[H_];
    __shared__ float accs[128];
    srel[tid & 255] = rel[b * R_ + (tid & 255)];
    for (int i = tid; i < H_; i += 256) spool[i] = pool[b * H_ + i];
    __syncthreads();
    int kk = tid & 127, half = tid >> 7;
    int k = q * 128 + kk;
    float acc = 0.f;
    if (half == 0) {
        acc = Wr_b[k] + Wg_b[k] + Wh_b[k];
        const float4* wr = (const float4*)(Wr_w + (size_t)k * R_);
        #pragma unroll 8
        for (int r4 = 0; r4 < R_ / 4; ++r4) {
            float4 w = wr[r4]; float4 x = ((const float4*)srel)[r4];
            acc += w.x * x.x + w.y * x.y + w.z * x.z + w.w * x.w;
        }
        const float4* wg = (const float4*)(Wg_w + (size_t)k * H_);
        #pragma unroll 8
        for (int h4 = 0; h4 < 32; ++h4) {
            float4 w = wg[h4]; float4 x = ((const float4*)spool)[h4];
            acc += w.x * x.x + w.y * x.y + w.z * x.z + w.w * x.w;
        }
    } else {
        const float4* wg = (const float4*)(Wg_w + (size_t)k * H_);
        #pragma unroll 8
        for (int h4 = 32; h4 < 128; ++h4) {
            float4 w = wg[h4]; float4 x = ((const float4*)spool)[h4];
            acc += w.x * x.x + w.y * x.y + w.z * x.z + w.w * x.w;
        }
    }
    if (half) accs[kk] = acc;
    __syncthreads();
    if (!half) base[b * H_ + k] = acc + accs[kk];
}

// ---------- K2: main GEMM [M,512]x[512,512]^T + tanh/alpha epilogue -> partial[4][M] ----------
// ROUND-4 version (best fused, 238.9 us). Round-5's deep register pipeline was silently
// collapsed by the register allocator (VGPR 124 << required ~230) and regressed; reverted.
__launch_bounds__(256)
__global__ void k_gemm(const float* __restrict__ A32,  // [M, 512] f32 (sent_h)
                       const u16* __restrict__ Bw,     // [512, 512] bf16 (Wh_w, B^T layout)
                       const float* __restrict__ base,  // [B_, H_]
                       const float* __restrict__ alpha, // [H_]
                       float* __restrict__ partial)     // [4][M]
{
    const int K = 512;
    int j = blockIdx.x;
    int xcd  = j & 7;
    int slot = j >> 3;
    int nb   = slot & 3;
    int mb   = (slot >> 2) * 8 + xcd;   // 0..1023, bijective over grid 4096
    int m0 = mb * 128;
    int n0 = nb * 128;
    int b  = m0 >> 11;   // m0 / S_

    int tid = threadIdx.x;
    int w  = tid >> 6;      // wave 0..3
    int l  = tid & 63;
    int wm = w & 1, wn = w >> 1;
    int lr = l & 15;        // C col / frag row
    int lq = l >> 4;        // quad

    __shared__ __attribute__((aligned(16))) u16 smA[2][128 * 64];   // 2 x 16 KB
    __shared__ __attribute__((aligned(16))) u16 smB[2][128 * 64];   // 2 x 16 KB
    __shared__ float red[2][2][64];

    f32x4 zero = {0.f, 0.f, 0.f, 0.f};
    f32x4 acc[4][4];
    #pragma unroll
    for (int i = 0; i < 4; ++i)
        #pragma unroll
        for (int jj = 0; jj < 4; ++jj) acc[i][jj] = zero;

    // per-chunk A geometry (chunk c = w*4+i): row = (c>>1)*16+lr, colgroup = (c&1)*32+lq*8
    int arow[4], acolg[4];
    #pragma unroll
    for (int i = 0; i < 4; ++i) {
        int c = w * 4 + i;
        arow[i]  = (c >> 1) * 16 + lr;
        acolg[i] = (c & 1) * 32 + lq * 8;
    }

    float4 av[4][2];   // in-flight A f32 (32 VGPR)

    auto LOAD_A = [&](int kt) {
        int k0 = kt * 64;
        #pragma unroll
        for (int i = 0; i < 4; ++i) {
            const float4* ga = (const float4*)(A32 + (size_t)(m0 + arow[i]) * K + k0 + acolg[i]);
            av[i][0] = ga[0];
            av[i][1] = ga[1];
        }
    };
    auto WRITE_A = [&](int buf) {
        #pragma unroll
        for (int i = 0; i < 4; ++i) {
            uint4 pv;
            pv.x = pk2(av[i][0].x, av[i][0].y);
            pv.y = pk2(av[i][0].z, av[i][0].w);
            pv.z = pk2(av[i][1].x, av[i][1].y);
            pv.w = pk2(av[i][1].z, av[i][1].w);
            *(uint4*)(smA[buf] + (w * 4 + i) * 512 + l * 8) = pv;
        }
    };
    auto STAGE_B = [&](int buf, int kt) {
        int k0 = kt * 64;
        #pragma unroll
        for (int i = 0; i < 4; ++i) {
            int c  = w * 4 + i;
            int mf = c >> 1, kc = c & 1;
            int row = mf * 16 + lr;
            int col = k0 + kc * 32 + lq * 8;
            const u16* gb = Bw + (size_t)(n0 + row) * K + col;
            load_lds16(gb, smB[buf] + c * 512);
        }
    };

    LOAD_A(0);         // oldest in vm queue
    STAGE_B(0, 0);
    WRITE_A(0);        // compiler waits vmcnt(4): A regs ready, B still in flight
    __syncthreads();   // drains B (vmcnt 0) + lgkm

    #pragma unroll
    for (int kt = 0; kt < 8; ++kt) {
        int cur = kt & 1;
        if (kt < 7) {
            LOAD_A(kt + 1);            // f32 A into regs (oldest)
            STAGE_B(cur ^ 1, kt + 1);  // B straight to LDS
        }
        __builtin_amdgcn_s_setprio(1);
        #pragma unroll
        for (int kc = 0; kc < 2; ++kc) {
            short8 af[4], bf[4];
            #pragma unroll
            for (int mi = 0; mi < 4; ++mi)
                af[mi] = *(const short8*)(smA[cur] + ((wm * 4 + mi) * 2 + kc) * 512 + l * 8);
            #pragma unroll
            for (int ni = 0; ni < 4; ++ni)
                bf[ni] = *(const short8*)(smB[cur] + ((wn * 4 + ni) * 2 + kc) * 512 + l * 8);
            #pragma unroll
            for (int mi = 0; mi < 4; ++mi)
                #pragma unroll
                for (int ni = 0; ni < 4; ++ni)
                    acc[mi][ni] = __builtin_amdgcn_mfma_f32_16x16x32_bf16(af[mi], bf[ni], acc[mi][ni], 0, 0, 0);
        }
        __builtin_amdgcn_s_setprio(0);
        if (kt < 7) WRITE_A(cur ^ 1);  // A loads had the whole MFMA phase to land
        __syncthreads();
    }

    // epilogue: sum_n tanh(acc + base[b,n]) * alpha[n] = sum(a) - sum 2a/(exp2(C2*v)+1)
    const float C2 = 2.8853900817779268f;   // 2*log2(e)
    float base2[4], a2[4];
    float asum = 0.f;
    #pragma unroll
    for (int ni = 0; ni < 4; ++ni) {
        int n = n0 + wn * 64 + ni * 16 + lr;
        base2[ni] = C2 * base[b * H_ + n];
        float al  = alpha[n];
        a2[ni] = 2.0f * al;
        asum  += al;
    }
    #pragma unroll
    for (int mi = 0; mi < 4; ++mi) {
        #pragma unroll
        for (int r = 0; r < 4; ++r) {
            float s = asum;
            #pragma unroll
            for (int ni = 0; ni < 4; ++ni) {
                float f  = fmaf(acc[mi][ni][r], C2, base2[ni]);
                float e  = __builtin_amdgcn_exp2f(f);
                float rr = __builtin_amdgcn_rcpf(e + 1.0f);
                s = fmaf(-a2[ni], rr, s);
            }
            s += __shfl_xor(s, 1);
            s += __shfl_xor(s, 2);
            s += __shfl_xor(s, 4);
            s += __shfl_xor(s, 8);
            if (lr == 0) red[wm][wn][mi * 16 + lq * 4 + r] = s;
        }
    }
    __syncthreads();
    if (tid < 128) {
        int wmi = tid >> 6, row = tid & 63;
        float sum = red[wmi][0][row] + red[wmi][1][row];
        partial[(size_t)nb * M_ + m0 + wmi * 64 + row] = sum;
    }
}

// ---------- K3: softmax over S per b ----------
__global__ void k_softmax(const float* __restrict__ partial, const int* __restrict__ mask,
                          const float* __restrict__ alpha_b, float* __restrict__ wout) {
    int b = blockIdx.x;
    int tid = threadIdx.x;
    __shared__ float sred[8];
    float x[8];
    float ab = alpha_b[0];
    float lmax = -3.0e38f;
    #pragma unroll
    for (int jj = 0; jj < 8; ++jj) {
        int s = tid + jj * 256;
        size_t m = (size_t)b * S_ + s;
        float v = partial[m] + partial[(size_t)M_ + m] + partial[2 * (size_t)M_ + m] + partial[3 * (size_t)M_ + m] + ab;
        if (mask[b * S_ + s] == 0) v = NEGV;
        x[jj] = v;
        lmax = fmaxf(lmax, v);
    }
    #pragma unroll
    for (int off = 1; off < 64; off <<= 1) lmax = fmaxf(lmax, __shfl_xor(lmax, off));
    int wv = tid >> 6, l = tid & 63;
    if (l == 0) sred[wv] = lmax;
    __syncthreads();
    float gmax = fmaxf(fmaxf(sred[0], sred[1]), fmaxf(sred[2], sred[3]));
    float lsum = 0.f;
    #pragma unroll
    for (int jj = 0; jj < 8; ++jj) { x[jj] = __expf(x[jj] - gmax); lsum += x[jj]; }
    #pragma unroll
    for (int off = 1; off < 64; off <<= 1) lsum += __shfl_xor(lsum, off);
    if (l == 0) sred[4 + wv] = lsum;
    __syncthreads();
    float inv = 1.f / (sred[4] + sred[5] + sred[6] + sred[7]);
    #pragma unroll
    for (int jj = 0; jj < 8; ++jj) {
        int s = tid + jj * 256;
        wout[(size_t)b * S_ + s] = x[jj] * inv;
    }
}

// ---------- K4: tpart[ss][b][h] = sum_{s in slice ss} w[b,s] * sent_h[b,s,h] ----------
// Contiguous-footprint rebuild: each block owns a 128-row s-slice and ALL 512 cols, so
// every 8-row step reads 16 KB perfectly sequential (thread tid = cols 2tid..2tid+1,
// 512B/wave contiguous, full 2KB DRAM rows). Old col-slice layout read 256B chunks at
// 2KB stride -> DRAM page thrash (suspected ~1 TB/s). Grid 64*16=1024 blocks (4/CU).
__global__ void k_wsum(const float* __restrict__ sent, const float* __restrict__ wrow_g,
                       float* __restrict__ tpart) {
    int b  = blockIdx.x >> 4;
    int ss = blockIdx.x & 15;
    int tid = threadIdx.x;
    __shared__ float wrow[128];
    if (tid < 128) wrow[tid] = wrow_g[(size_t)b * S_ + ss * 128 + tid];
    __syncthreads();
    const float* bp = sent + ((size_t)b * S_ + (size_t)ss * 128) * H_ + tid * 2;
    float ax = 0.f, ay = 0.f;
    for (int r0 = 0; r0 < 128; r0 += 8) {
        float2 v[8];
        #pragma unroll
        for (int u = 0; u < 8; ++u)
            v[u] = *(const float2*)(bp + (size_t)(r0 + u) * H_);
        #pragma unroll
        for (int u = 0; u < 8; ++u) {
            float wgt = wrow[r0 + u];
            ax = fmaf(wgt, v[u].x, ax);
            ay = fmaf(wgt, v[u].y, ay);
        }
    }
    float* tp = tpart + ((size_t)ss * B_ + b) * H_ + tid * 2;
    tp[0] = ax; tp[1] = ay;
}

// ---------- K5: att_res[b,h] = Wh_b[h] + sum_h' (sum_ss tpart[ss][b][h']) * Wh_w[h,h'] ----------
__global__ void k_att(const float* __restrict__ tpart, const float* __restrict__ Whw,
                      const float* __restrict__ Whb, float* __restrict__ out) {
    int tid = threadIdx.x;
    int b = blockIdx.x >> 2, q = blockIdx.x & 3;
    __shared__ __attribute__((aligned(16))) float st[H_];
    __shared__ float accs[128];
    for (int i = tid; i < H_; i += 256) {
        float s = 0.f;
        #pragma unroll
        for (int ss = 0; ss < 16; ++ss)
            s += tpart[((size_t)ss * B_ + b) * H_ + i];
        st[i] = s;
    }
    __syncthreads();
    int hh = tid & 127, half = tid >> 7;
    int h = q * 128 + hh;
    const float4* wr = (const float4*)(Whw + (size_t)h * H_) + half * 64;
    const float4* sx = (const float4*)st + half * 64;
    float acc = 0.f;
    #pragma unroll 8
    for (int i = 0; i < 64; ++i) {
        float4 w = wr[i]; float4 x = sx[i];
        acc += w.x * x.x + w.y * x.y + w.z * x.z + w.w * x.w;
    }
    if (half) accs[hh] = acc;
    __syncthreads();
    if (!half) out[(size_t)b * H_ + h] = acc + accs[hh] + Whb[h];
}

extern "C" void kernel_launch(void* const* d_in, const int* in_sizes, int n_in,
                              void* d_out, int out_size, void* d_ws, size_t ws_size,
                              hipStream_t stream) {
    const float* sent_h  = (const float*)d_in[0];
    const float* rel     = (const float*)d_in[1];
    const float* pool    = (const float*)d_in[2];
    const int*   mask    = (const int*)d_in[3];
    const float* Wg_w    = (const float*)d_in[4];
    const float* Wg_b    = (const float*)d_in[5];
    const float* Wh_w    = (const float*)d_in[6];
    const float* Wh_b    = (const float*)d_in[7];
    const float* Wr_w    = (const float*)d_in[8];
    const float* Wr_b    = (const float*)d_in[9];
    const float* alpha_w = (const float*)d_in[10];
    const float* alpha_b = (const float*)d_in[11];
    float* out = (float*)d_out;

    char* ws = (char*)d_ws;
    u16*   whwb    = (u16*)ws;                       // 524288 B
    float* base    = (float*)(ws + 524288);          // 131072 B
    float* partial = (float*)(ws + 524288 + 131072); // 2097152 B
    float* tpart   = (float*)(ws + 524288 + 131072 + 2097152); // 2097152 B

    float* att_out = out;             // [64,512]
    float* w_out   = out + B_ * H_;   // [64,2048]

    k_base<<<dim3(256), dim3(256), 0, stream>>>(rel, pool, Wg_w, Wg_b, Wh_b, Wr_w, Wr_b, Wh_w, base, whwb);
    k_gemm<<<dim3((M_ / 128) * 4), dim3(256), 0, stream>>>(sent_h, whwb, base, alpha_w, partial);
    k_softmax<<<dim3(B_), dim3(256), 0, stream>>>(partial, mask, alpha_b, w_out);
    k_wsum<<<dim3(B_ * 16), dim3(256), 0, stream>>>(sent_h, w_out, tpart);
    k_att<<<dim3(256), dim3(256), 0, stream>>>(tpart, Wh_w, Wh_b, att_out);
}

// Round 7
// 566.757 us; speedup vs baseline: 1.0373x; 1.0101x over previous
//
#include <hip/hip_runtime.h>
#include <cstdint>
#include <cstddef>

#define B_ 64
#define S_ 2048
#define H_ 512
#define R_ 256
#define M_ (B_ * S_)   // 131072
#define NEGV (-1.0e9f)

typedef short short8 __attribute__((ext_vector_type(8)));
typedef unsigned short u16x8 __attribute__((ext_vector_type(8)));
typedef float f32x4 __attribute__((ext_vector_type(4)));
typedef unsigned short u16;

#define VMCNT(N)  asm volatile("s_waitcnt vmcnt(" #N ")" ::: "memory")
#define LGKM0()   asm volatile("s_waitcnt lgkmcnt(0)" ::: "memory")

// ---------- helpers ----------
__device__ __forceinline__ u16 f2b(float x) {
    union { float f; uint32_t u; } c; c.f = x;
    uint32_t u = c.u;
    uint32_t r = (u + 0x7fffu + ((u >> 16) & 1u)) >> 16;   // RNE
    return (u16)r;
}
__device__ __forceinline__ float b2f(u16 u) {
    union { uint32_t u; float f; } c; c.u = ((uint32_t)u) << 16;
    return c.f;
}
// HW packed f32->bf16 (RNE, identical result to f2b)
__device__ __forceinline__ uint32_t pk2(float lo, float hi) {
    uint32_t r;
    asm("v_cvt_pk_bf16_f32 %0, %1, %2" : "=v"(r) : "v"(lo), "v"(hi));
    return r;
}
// asm global load: opaque to the register allocator -> cannot be sunk (round-5 failure mode)
__device__ __forceinline__ float4 gload4(const float4* p) {
    float4 d;
    asm volatile("global_load_dwordx4 %0, %1, off" : "=v"(d) : "v"(p));
    return d;
}
__device__ __forceinline__ void load_lds16(const void* g, void* l) {
    __builtin_amdgcn_global_load_lds((__attribute__((address_space(1))) void*)g,
                                     (__attribute__((address_space(3))) void*)l,
                                     16, 0, 0);
}

// ---------- K1: base[b,k] = rel@Wr^T + Wr_b + pool@Wg^T + Wg_b + Wh_b  (+ Wh_w f32->bf16) ----------
__global__ void k_base(const float* __restrict__ rel, const float* __restrict__ pool,
                       const float* __restrict__ Wg_w, const float* __restrict__ Wg_b,
                       const float* __restrict__ Wh_b,
                       const float* __restrict__ Wr_w, const float* __restrict__ Wr_b,
                       const float* __restrict__ whw, float* __restrict__ base,
                       u16* __restrict__ whwb) {
    int tid = threadIdx.x;
    {   // convert Wh_w: 262144 elems = 65536 float4 groups; exactly one per thread
        int gi = blockIdx.x * 256 + tid;
        float4 v = ((const float4*)whw)[gi];
        ushort4 o; o.x = f2b(v.x); o.y = f2b(v.y); o.z = f2b(v.z); o.w = f2b(v.w);
        ((ushort4*)whwb)[gi] = o;
    }
    int b = blockIdx.x >> 2, q = blockIdx.x & 3;
    __shared__ __attribute__((aligned(16))) float srel[R_];
    __shared__ __attribute__((aligned(16))) float spool[H_];
    __shared__ float accs[128];
    srel[tid & 255] = rel[b * R_ + (tid & 255)];
    for (int i = tid; i < H_; i += 256) spool[i] = pool[b * H_ + i];
    __syncthreads();
    int kk = tid & 127, half = tid >> 7;
    int k = q * 128 + kk;
    float acc = 0.f;
    if (half == 0) {
        acc = Wr_b[k] + Wg_b[k] + Wh_b[k];
        const float4* wr = (const float4*)(Wr_w + (size_t)k * R_);
        #pragma unroll 8
        for (int r4 = 0; r4 < R_ / 4; ++r4) {
            float4 w = wr[r4]; float4 x = ((const float4*)srel)[r4];
            acc += w.x * x.x + w.y * x.y + w.z * x.z + w.w * x.w;
        }
        const float4* wg = (const float4*)(Wg_w + (size_t)k * H_);
        #pragma unroll 8
        for (int h4 = 0; h4 < 32; ++h4) {
            float4 w = wg[h4]; float4 x = ((const float4*)spool)[h4];
            acc += w.x * x.x + w.y * x.y + w.z * x.z + w.w * x.w;
        }
    } else {
        const float4* wg = (const float4*)(Wg_w + (size_t)k * H_);
        #pragma unroll 8
        for (int h4 = 32; h4 < 128; ++h4) {
            float4 w = wg[h4]; float4 x = ((const float4*)spool)[h4];
            acc += w.x * x.x + w.y * x.y + w.z * x.z + w.w * x.w;
        }
    }
    if (half) accs[kk] = acc;
    __syncthreads();
    if (!half) base[b * H_ + k] = acc + accs[kk];
}

// ---------- K2: main GEMM [M,512]x[512,512]^T + tanh/alpha epilogue -> partial[4][M] ----------
// v6 = round-4 layout + T4 counted-vmcnt schedule:
//  - A (f32) loaded via asm-volatile global_load_dwordx4 into a 2-deep register pipeline
//    (slot kt&1), issued TWO K-steps ahead -> ~1200cy load->use window.
//  - B staged one step ahead via global_load_lds (unchanged).
//  - Barriers are raw s_barrier with HAND-COUNTED waits. Issue ledger per iter kt
//    (outstanding VMEM, issue order): A(kt+1)[8] | B(kt+1)[4] | A(kt+2)[8]  = 20.
//      WRITE_A needs A(kt+1)  -> vmcnt(12)
//      barrier needs B(kt+1)  -> vmcnt(8)   (A(kt+2) stays in flight ACROSS the barrier)
//    The VM queue is never fully drained until kt=6 -> removes round-4's per-step
//    vmcnt(0) drain, which was the ~10x latency serializer (0.6 TB/s at 12% MfmaUtil).
__launch_bounds__(256)
__global__ void k_gemm(const float* __restrict__ A32,  // [M, 512] f32 (sent_h)
                       const u16* __restrict__ Bw,     // [512, 512] bf16 (Wh_w, B^T layout)
                       const float* __restrict__ base,  // [B_, H_]
                       const float* __restrict__ alpha, // [H_]
                       float* __restrict__ partial)     // [4][M]
{
    const int K = 512;
    int j = blockIdx.x;
    int xcd  = j & 7;
    int slot0 = j >> 3;
    int nb   = slot0 & 3;
    int mb   = (slot0 >> 2) * 8 + xcd;   // 0..1023, bijective over grid 4096
    int m0 = mb * 128;
    int n0 = nb * 128;
    int b  = m0 >> 11;   // m0 / S_

    int tid = threadIdx.x;
    int w  = tid >> 6;      // wave 0..3
    int l  = tid & 63;
    int wm = w & 1, wn = w >> 1;
    int lr = l & 15;        // C col / frag row
    int lq = l >> 4;        // quad

    __shared__ __attribute__((aligned(16))) u16 smA[2][128 * 64];   // 2 x 16 KB
    __shared__ __attribute__((aligned(16))) u16 smB[2][128 * 64];   // 2 x 16 KB
    __shared__ float red[2][2][64];

    f32x4 zero = {0.f, 0.f, 0.f, 0.f};
    f32x4 acc[4][4];
    #pragma unroll
    for (int i = 0; i < 4; ++i)
        #pragma unroll
        for (int jj = 0; jj < 4; ++jj) acc[i][jj] = zero;

    // per-chunk A geometry (chunk c = w*4+i): row = (c>>1)*16+lr, colgroup = (c&1)*32+lq*8
    int arow[4], acolg[4];
    #pragma unroll
    for (int i = 0; i < 4; ++i) {
        int c = w * 4 + i;
        arow[i]  = (c >> 1) * 16 + lr;
        acolg[i] = (c & 1) * 32 + lq * 8;
    }

    float4 av[2][4][2];   // 2-slot A pipeline, pinned by asm loads (64 VGPR)

    auto LOAD_A = [&](int slot, int kt) {   // 8 asm loads, program-ordered
        int k0 = kt * 64;
        #pragma unroll
        for (int i = 0; i < 4; ++i) {
            const float4* ga = (const float4*)(A32 + (size_t)(m0 + arow[i]) * K + k0 + acolg[i]);
            av[slot][i][0] = gload4(ga);
            av[slot][i][1] = gload4(ga + 1);
        }
    };
    auto WRITE_A = [&](int buf, int slot) {
        #pragma unroll
        for (int i = 0; i < 4; ++i) {
            uint4 pv;
            pv.x = pk2(av[slot][i][0].x, av[slot][i][0].y);
            pv.y = pk2(av[slot][i][0].z, av[slot][i][0].w);
            pv.z = pk2(av[slot][i][1].x, av[slot][i][1].y);
            pv.w = pk2(av[slot][i][1].z, av[slot][i][1].w);
            *(uint4*)(smA[buf] + (w * 4 + i) * 512 + l * 8) = pv;
        }
    };
    auto STAGE_B = [&](int buf, int kt) {   // 4 global_load_lds
        int k0 = kt * 64;
        #pragma unroll
        for (int i = 0; i < 4; ++i) {
            int c  = w * 4 + i;
            int mf = c >> 1, kc = c & 1;
            int row = mf * 16 + lr;
            int col = k0 + kc * 32 + lq * 8;
            const u16* gb = Bw + (size_t)(n0 + row) * K + col;
            load_lds16(gb, smB[buf] + c * 512);
        }
    };

    // prologue. queue after issues: A0(8), B0(4), A1(8) = 20
    LOAD_A(0, 0);
    STAGE_B(0, 0);
    LOAD_A(1, 1);
    VMCNT(12); __builtin_amdgcn_sched_barrier(0);   // A0 landed
    WRITE_A(0, 0);
    VMCNT(8);                                        // B0 landed (A1 in flight)
    LGKM0();
    __builtin_amdgcn_s_barrier();

    #pragma unroll
    for (int kt = 0; kt < 8; ++kt) {
        const int cur = kt & 1, nxt = cur ^ 1;
        __builtin_amdgcn_sched_barrier(0);
        // issue next work first (covered by compute below)
        if (kt < 7) STAGE_B(nxt, kt + 1);       // +4
        if (kt < 6) LOAD_A(cur, kt + 2);        // +8  (slot cur was consumed last iter)
        // queue: A(kt+1)[8] , B(kt+1)[4] , A(kt+2)[8]
        __builtin_amdgcn_s_setprio(1);
        #pragma unroll
        for (int kc = 0; kc < 2; ++kc) {
            short8 af[4], bf[4];
            #pragma unroll
            for (int mi = 0; mi < 4; ++mi)
                af[mi] = *(const short8*)(smA[cur] + ((wm * 4 + mi) * 2 + kc) * 512 + l * 8);
            #pragma unroll
            for (int ni = 0; ni < 4; ++ni)
                bf[ni] = *(const short8*)(smB[cur] + ((wn * 4 + ni) * 2 + kc) * 512 + l * 8);
            #pragma unroll
            for (int mi = 0; mi < 4; ++mi)
                #pragma unroll
                for (int ni = 0; ni < 4; ++ni)
                    acc[mi][ni] = __builtin_amdgcn_mfma_f32_16x16x32_bf16(af[mi], bf[ni], acc[mi][ni], 0, 0, 0);
        }
        __builtin_amdgcn_s_setprio(0);
        if (kt < 7) {
            // wait A(kt+1) only: leave B(kt+1)+A(kt+2) in flight
            if (kt < 6) { VMCNT(12); } else { VMCNT(4); }
            __builtin_amdgcn_sched_barrier(0);
            WRITE_A(nxt, (kt + 1) & 1);
            // barrier needs B(kt+1) complete; A(kt+2) rides across
            if (kt < 6) { VMCNT(8); } else { VMCNT(0); }
        }
        LGKM0();
        __builtin_amdgcn_s_barrier();
    }
    __builtin_amdgcn_sched_barrier(0);

    // epilogue: sum_n tanh(acc + base[b,n]) * alpha[n] = sum(a) - sum 2a/(exp2(C2*v)+1)
    const float C2 = 2.8853900817779268f;   // 2*log2(e)
    float base2[4], a2[4];
    float asum = 0.f;
    #pragma unroll
    for (int ni = 0; ni < 4; ++ni) {
        int n = n0 + wn * 64 + ni * 16 + lr;
        base2[ni] = C2 * base[b * H_ + n];
        float al  = alpha[n];
        a2[ni] = 2.0f * al;
        asum  += al;
    }
    #pragma unroll
    for (int mi = 0; mi < 4; ++mi) {
        #pragma unroll
        for (int r = 0; r < 4; ++r) {
            float s = asum;
            #pragma unroll
            for (int ni = 0; ni < 4; ++ni) {
                float f  = fmaf(acc[mi][ni][r], C2, base2[ni]);
                float e  = __builtin_amdgcn_exp2f(f);
                float rr = __builtin_amdgcn_rcpf(e + 1.0f);
                s = fmaf(-a2[ni], rr, s);
            }
            s += __shfl_xor(s, 1);
            s += __shfl_xor(s, 2);
            s += __shfl_xor(s, 4);
            s += __shfl_xor(s, 8);
            if (lr == 0) red[wm][wn][mi * 16 + lq * 4 + r] = s;
        }
    }
    __syncthreads();
    if (tid < 128) {
        int wmi = tid >> 6, row = tid & 63;
        float sum = red[wmi][0][row] + red[wmi][1][row];
        partial[(size_t)nb * M_ + m0 + wmi * 64 + row] = sum;
    }
}

// ---------- K3: softmax over S per b ----------
__global__ void k_softmax(const float* __restrict__ partial, const int* __restrict__ mask,
                          const float* __restrict__ alpha_b, float* __restrict__ wout) {
    int b = blockIdx.x;
    int tid = threadIdx.x;
    __shared__ float sred[8];
    float x[8];
    float ab = alpha_b[0];
    float lmax = -3.0e38f;
    #pragma unroll
    for (int jj = 0; jj < 8; ++jj) {
        int s = tid + jj * 256;
        size_t m = (size_t)b * S_ + s;
        float v = partial[m] + partial[(size_t)M_ + m] + partial[2 * (size_t)M_ + m] + partial[3 * (size_t)M_ + m] + ab;
        if (mask[b * S_ + s] == 0) v = NEGV;
        x[jj] = v;
        lmax = fmaxf(lmax, v);
    }
    #pragma unroll
    for (int off = 1; off < 64; off <<= 1) lmax = fmaxf(lmax, __shfl_xor(lmax, off));
    int wv = tid >> 6, l = tid & 63;
    if (l == 0) sred[wv] = lmax;
    __syncthreads();
    float gmax = fmaxf(fmaxf(sred[0], sred[1]), fmaxf(sred[2], sred[3]));
    float lsum = 0.f;
    #pragma unroll
    for (int jj = 0; jj < 8; ++jj) { x[jj] = __expf(x[jj] - gmax); lsum += x[jj]; }
    #pragma unroll
    for (int off = 1; off < 64; off <<= 1) lsum += __shfl_xor(lsum, off);
    if (l == 0) sred[4 + wv] = lsum;
    __syncthreads();
    float inv = 1.f / (sred[4] + sred[5] + sred[6] + sred[7]);
    #pragma unroll
    for (int jj = 0; jj < 8; ++jj) {
        int s = tid + jj * 256;
        wout[(size_t)b * S_ + s] = x[jj] * inv;
    }
}

// ---------- K4: tpart[ss][b][h] = sum_{s in slice ss} w[b,s] * sent_h[b,s,h] ----------
__global__ void k_wsum(const float* __restrict__ sent, const float* __restrict__ wrow_g,
                       float* __restrict__ tpart) {
    int b  = blockIdx.x >> 4;
    int ss = blockIdx.x & 15;
    int tid = threadIdx.x;
    __shared__ float wrow[128];
    if (tid < 128) wrow[tid] = wrow_g[(size_t)b * S_ + ss * 128 + tid];
    __syncthreads();
    const float* bp = sent + ((size_t)b * S_ + (size_t)ss * 128) * H_ + tid * 2;
    float ax = 0.f, ay = 0.f;
    for (int r0 = 0; r0 < 128; r0 += 8) {
        float2 v[8];
        #pragma unroll
        for (int u = 0; u < 8; ++u)
            v[u] = *(const float2*)(bp + (size_t)(r0 + u) * H_);
        #pragma unroll
        for (int u = 0; u < 8; ++u) {
            float wgt = wrow[r0 + u];
            ax = fmaf(wgt, v[u].x, ax);
            ay = fmaf(wgt, v[u].y, ay);
        }
    }
    float* tp = tpart + ((size_t)ss * B_ + b) * H_ + tid * 2;
    tp[0] = ax; tp[1] = ay;
}

// ---------- K5: att_res[b,h] = Wh_b[h] + sum_h' (sum_ss tpart[ss][b][h']) * Wh_w[h,h'] ----------
__global__ void k_att(const float* __restrict__ tpart, const float* __restrict__ Whw,
                      const float* __restrict__ Whb, float* __restrict__ out) {
    int tid = threadIdx.x;
    int b = blockIdx.x >> 2, q = blockIdx.x & 3;
    __shared__ __attribute__((aligned(16))) float st[H_];
    __shared__ float accs[128];
    for (int i = tid; i < H_; i += 256) {
        float s = 0.f;
        #pragma unroll
        for (int ss = 0; ss < 16; ++ss)
            s += tpart[((size_t)ss * B_ + b) * H_ + i];
        st[i] = s;
    }
    __syncthreads();
    int hh = tid & 127, half = tid >> 7;
    int h = q * 128 + hh;
    const float4* wr = (const float4*)(Whw + (size_t)h * H_) + half * 64;
    const float4* sx = (const float4*)st + half * 64;
    float acc = 0.f;
    #pragma unroll 8
    for (int i = 0; i < 64; ++i) {
        float4 w = wr[i]; float4 x = sx[i];
        acc += w.x * x.x + w.y * x.y + w.z * x.z + w.w * x.w;
    }
    if (half) accs[hh] = acc;
    __syncthreads();
    if (!half) out[(size_t)b * H_ + h] = acc + accs[hh] + Whb[h];
}

extern "C" void kernel_launch(void* const* d_in, const int* in_sizes, int n_in,
                              void* d_out, int out_size, void* d_ws, size_t ws_size,
                              hipStream_t stream) {
    const float* sent_h  = (const float*)d_in[0];
    const float* rel     = (const float*)d_in[1];
    const float* pool    = (const float*)d_in[2];
    const int*   mask    = (const int*)d_in[3];
    const float* Wg_w    = (const float*)d_in[4];
    const float* Wg_b    = (const float*)d_in[5];
    const float* Wh_w    = (const float*)d_in[6];
    const float* Wh_b    = (const float*)d_in[7];
    const float* Wr_w    = (const float*)d_in[8];
    const float* Wr_b    = (const float*)d_in[9];
    const float* alpha_w = (const float*)d_in[10];
    const float* alpha_b = (const float*)d_in[11];
    float* out = (float*)d_out;

    char* ws = (char*)d_ws;
    u16*   whwb    = (u16*)ws;                       // 524288 B
    float* base    = (float*)(ws + 524288);          // 131072 B
    float* partial = (float*)(ws + 524288 + 131072); // 2097152 B
    float* tpart   = (float*)(ws + 524288 + 131072 + 2097152); // 2097152 B

    float* att_out = out;             // [64,512]
    float* w_out   = out + B_ * H_;   // [64,2048]

    k_base<<<dim3(256), dim3(256), 0, stream>>>(rel, pool, Wg_w, Wg_b, Wh_b, Wr_w, Wr_b, Wh_w, base, whwb);
    k_gemm<<<dim3((M_ / 128) * 4), dim3(256), 0, stream>>>(sent_h, whwb, base, alpha_w, partial);
    k_softmax<<<dim3(B_), dim3(256), 0, stream>>>(partial, mask, alpha_b, w_out);
    k_wsum<<<dim3(B_ * 16), dim3(256), 0, stream>>>(sent_h, w_out, tpart);
    k_att<<<dim3(256), dim3(256), 0, stream>>>(tpart, Wh_w, Wh_b, att_out);
}

// Round 8
// 547.016 us; speedup vs baseline: 1.0747x; 1.0361x over previous
//
#include <hip/hip_runtime.h>
#include <cstdint>
#include <cstddef>

#define B_ 64
#define S_ 2048
#define H_ 512
#define R_ 256
#define M_ (B_ * S_)   // 131072
#define NEGV (-1.0e9f)

typedef short short8 __attribute__((ext_vector_type(8)));
typedef unsigned short u16x8 __attribute__((ext_vector_type(8)));
typedef float f32x4 __attribute__((ext_vector_type(4)));
typedef unsigned short u16;

// ---------- helpers ----------
__device__ __forceinline__ u16 f2b(float x) {
    union { float f; uint32_t u; } c; c.f = x;
    uint32_t u = c.u;
    uint32_t r = (u + 0x7fffu + ((u >> 16) & 1u)) >> 16;   // RNE
    return (u16)r;
}
__device__ __forceinline__ float b2f(u16 u) {
    union { uint32_t u; float f; } c; c.u = ((uint32_t)u) << 16;
    return c.f;
}
// HW packed f32->bf16 (RNE, identical result to f2b)
__device__ __forceinline__ uint32_t pk2(float lo, float hi) {
    uint32_t r;
    asm("v_cvt_pk_bf16_f32 %0, %1, %2" : "=v"(r) : "v"(lo), "v"(hi));
    return r;
}
__device__ __forceinline__ void load_lds16(const void* g, void* l) {
    __builtin_amdgcn_global_load_lds((__attribute__((address_space(1))) void*)g,
                                     (__attribute__((address_space(3))) void*)l,
                                     16, 0, 0);
}

// ---------- K1: base[b,k] = rel@Wr^T + Wr_b + pool@Wg^T + Wg_b + Wh_b  (+ Wh_w f32->bf16) ----------
__global__ void k_base(const float* __restrict__ rel, const float* __restrict__ pool,
                       const float* __restrict__ Wg_w, const float* __restrict__ Wg_b,
                       const float* __restrict__ Wh_b,
                       const float* __restrict__ Wr_w, const float* __restrict__ Wr_b,
                       const float* __restrict__ whw, float* __restrict__ base,
                       u16* __restrict__ whwb) {
    int tid = threadIdx.x;
    {   // convert Wh_w: 262144 elems = 65536 float4 groups; exactly one per thread
        int gi = blockIdx.x * 256 + tid;
        float4 v = ((const float4*)whw)[gi];
        ushort4 o; o.x = f2b(v.x); o.y = f2b(v.y); o.z = f2b(v.z); o.w = f2b(v.w);
        ((ushort4*)whwb)[gi] = o;
    }
    int b = blockIdx.x >> 2, q = blockIdx.x & 3;
    __shared__ __attribute__((aligned(16))) float srel[R_];
    __shared__ __attribute__((aligned(16))) float spool[H_];
    __shared__ float accs[128];
    srel[tid & 255] = rel[b * R_ + (tid & 255)];
    for (int i = tid; i < H_; i += 256) spool[i] = pool[b * H_ + i];
    __syncthreads();
    int kk = tid & 127, half = tid >> 7;
    int k = q * 128 + kk;
    float acc = 0.f;
    if (half == 0) {
        acc = Wr_b[k] + Wg_b[k] + Wh_b[k];
        const float4* wr = (const float4*)(Wr_w + (size_t)k * R_);
        #pragma unroll 8
        for (int r4 = 0; r4 < R_ / 4; ++r4) {
            float4 w = wr[r4]; float4 x = ((const float4*)srel)[r4];
            acc += w.x * x.x + w.y * x.y + w.z * x.z + w.w * x.w;
        }
        const float4* wg = (const float4*)(Wg_w + (size_t)k * H_);
        #pragma unroll 8
        for (int h4 = 0; h4 < 32; ++h4) {
            float4 w = wg[h4]; float4 x = ((const float4*)spool)[h4];
            acc += w.x * x.x + w.y * x.y + w.z * x.z + w.w * x.w;
        }
    } else {
        const float4* wg = (const float4*)(Wg_w + (size_t)k * H_);
        #pragma unroll 8
        for (int h4 = 32; h4 < 128; ++h4) {
            float4 w = wg[h4]; float4 x = ((const float4*)spool)[h4];
            acc += w.x * x.x + w.y * x.y + w.z * x.z + w.w * x.w;
        }
    }
    if (half) accs[kk] = acc;
    __syncthreads();
    if (!half) base[b * H_ + k] = acc + accs[kk];
}

// ---------- K2: main GEMM [M,512]x[512,512]^T + tanh/alpha epilogue -> partial[4][M] ----------
// v7 = round-4 dataflow with BK=32 (was 64): LDS 66.5 -> 33.8 KB => 4 blocks/CU
// (16 waves, was 2 blocks/8 waves). Clean single-variable occupancy test: per-step
// latency exposure is unchanged, but 4 independent blocks now interleave at each
// barrier stall instead of 2. 16 K-steps x 16 MFMA. A f32 reg-staged + cvt_pk,
// B via global_load_lds, plain __syncthreads (counted-vmcnt was neutral, r7).
__launch_bounds__(256, 4)
__global__ void k_gemm(const float* __restrict__ A32,  // [M, 512] f32 (sent_h)
                       const u16* __restrict__ Bw,     // [512, 512] bf16 (Wh_w, B^T layout)
                       const float* __restrict__ base,  // [B_, H_]
                       const float* __restrict__ alpha, // [H_]
                       float* __restrict__ partial)     // [4][M]
{
    const int K = 512;
    const int NT = 16;                  // K-steps (BK=32)
    int j = blockIdx.x;
    int xcd  = j & 7;
    int slot = j >> 3;
    int nb   = slot & 3;
    int mb   = (slot >> 2) * 8 + xcd;   // 0..1023, bijective over grid 4096
    int m0 = mb * 128;
    int n0 = nb * 128;
    int b  = m0 >> 11;   // m0 / S_

    int tid = threadIdx.x;
    int w  = tid >> 6;      // wave 0..3
    int l  = tid & 63;
    int wm = w & 1, wn = w >> 1;
    int lr = l & 15;        // frag row within 16-row chunk / C col
    int lq = l >> 4;        // quad

    __shared__ __attribute__((aligned(16))) u16 smA[2][128 * 32];   // 2 x 8 KB
    __shared__ __attribute__((aligned(16))) u16 smB[2][128 * 32];   // 2 x 8 KB
    __shared__ float red[2][2][64];                                 // 1 KB

    f32x4 zero = {0.f, 0.f, 0.f, 0.f};
    f32x4 acc[4][4];
    #pragma unroll
    for (int i = 0; i < 4; ++i)
        #pragma unroll
        for (int jj = 0; jj < 4; ++jj) acc[i][jj] = zero;

    // chunk c = w*2+i (i=0,1): rows c*16..c*16+16, lane l -> row c*16+lr, cols lq*8..+8
    int arow[2];
    #pragma unroll
    for (int i = 0; i < 2; ++i) arow[i] = (w * 2 + i) * 16 + lr;

    float4 av[2][2];   // in-flight A f32 (16 VGPR)

    auto LOAD_A = [&](int kt) {
        int k0 = kt * 32;
        #pragma unroll
        for (int i = 0; i < 2; ++i) {
            const float4* ga = (const float4*)(A32 + (size_t)(m0 + arow[i]) * K + k0 + lq * 8);
            av[i][0] = ga[0];
            av[i][1] = ga[1];
        }
    };
    auto WRITE_A = [&](int buf) {
        #pragma unroll
        for (int i = 0; i < 2; ++i) {
            uint4 pv;
            pv.x = pk2(av[i][0].x, av[i][0].y);
            pv.y = pk2(av[i][0].z, av[i][0].w);
            pv.z = pk2(av[i][1].x, av[i][1].y);
            pv.w = pk2(av[i][1].z, av[i][1].w);
            *(uint4*)(smA[buf] + (w * 2 + i) * 512 + l * 8) = pv;
        }
    };
    auto STAGE_B = [&](int buf, int kt) {
        int k0 = kt * 32;
        #pragma unroll
        for (int i = 0; i < 2; ++i) {
            int c = w * 2 + i;
            const u16* gb = Bw + (size_t)(n0 + c * 16 + lr) * K + k0 + lq * 8;
            load_lds16(gb, smB[buf] + c * 512);
        }
    };

    LOAD_A(0);
    STAGE_B(0, 0);
    WRITE_A(0);        // compiler waits A regs; B still in flight
    __syncthreads();   // drains B + lgkm

    #pragma unroll
    for (int kt = 0; kt < NT; ++kt) {
        int cur = kt & 1;
        if (kt < NT - 1) {
            LOAD_A(kt + 1);            // f32 A into regs (oldest in queue)
            STAGE_B(cur ^ 1, kt + 1);  // B straight to LDS
        }
        __builtin_amdgcn_s_setprio(1);
        {
            short8 af[4], bf[4];
            #pragma unroll
            for (int mi = 0; mi < 4; ++mi)
                af[mi] = *(const short8*)(smA[cur] + (wm * 4 + mi) * 512 + l * 8);
            #pragma unroll
            for (int ni = 0; ni < 4; ++ni)
                bf[ni] = *(const short8*)(smB[cur] + (wn * 4 + ni) * 512 + l * 8);
            #pragma unroll
            for (int mi = 0; mi < 4; ++mi)
                #pragma unroll
                for (int ni = 0; ni < 4; ++ni)
                    acc[mi][ni] = __builtin_amdgcn_mfma_f32_16x16x32_bf16(af[mi], bf[ni], acc[mi][ni], 0, 0, 0);
        }
        __builtin_amdgcn_s_setprio(0);
        if (kt < NT - 1) WRITE_A(cur ^ 1);  // A loads had the whole MFMA phase to land
        __syncthreads();
    }

    // epilogue: sum_n tanh(acc + base[b,n]) * alpha[n] = sum(a) - sum 2a/(exp2(C2*v)+1)
    const float C2 = 2.8853900817779268f;   // 2*log2(e)
    float base2[4], a2[4];
    float asum = 0.f;
    #pragma unroll
    for (int ni = 0; ni < 4; ++ni) {
        int n = n0 + wn * 64 + ni * 16 + lr;
        base2[ni] = C2 * base[b * H_ + n];
        float al  = alpha[n];
        a2[ni] = 2.0f * al;
        asum  += al;
    }
    #pragma unroll
    for (int mi = 0; mi < 4; ++mi) {
        #pragma unroll
        for (int r = 0; r < 4; ++r) {
            float s = asum;
            #pragma unroll
            for (int ni = 0; ni < 4; ++ni) {
                float f  = fmaf(acc[mi][ni][r], C2, base2[ni]);
                float e  = __builtin_amdgcn_exp2f(f);
                float rr = __builtin_amdgcn_rcpf(e + 1.0f);
                s = fmaf(-a2[ni], rr, s);
            }
            s += __shfl_xor(s, 1);
            s += __shfl_xor(s, 2);
            s += __shfl_xor(s, 4);
            s += __shfl_xor(s, 8);
            if (lr == 0) red[wm][wn][mi * 16 + lq * 4 + r] = s;
        }
    }
    __syncthreads();
    if (tid < 128) {
        int wmi = tid >> 6, row = tid & 63;
        float sum = red[wmi][0][row] + red[wmi][1][row];
        partial[(size_t)nb * M_ + m0 + wmi * 64 + row] = sum;
    }
}

// ---------- K3: softmax over S per b ----------
__global__ void k_softmax(const float* __restrict__ partial, const int* __restrict__ mask,
                          const float* __restrict__ alpha_b, float* __restrict__ wout) {
    int b = blockIdx.x;
    int tid = threadIdx.x;
    __shared__ float sred[8];
    float x[8];
    float ab = alpha_b[0];
    float lmax = -3.0e38f;
    #pragma unroll
    for (int jj = 0; jj < 8; ++jj) {
        int s = tid + jj * 256;
        size_t m = (size_t)b * S_ + s;
        float v = partial[m] + partial[(size_t)M_ + m] + partial[2 * (size_t)M_ + m] + partial[3 * (size_t)M_ + m] + ab;
        if (mask[b * S_ + s] == 0) v = NEGV;
        x[jj] = v;
        lmax = fmaxf(lmax, v);
    }
    #pragma unroll
    for (int off = 1; off < 64; off <<= 1) lmax = fmaxf(lmax, __shfl_xor(lmax, off));
    int wv = tid >> 6, l = tid & 63;
    if (l == 0) sred[wv] = lmax;
    __syncthreads();
    float gmax = fmaxf(fmaxf(sred[0], sred[1]), fmaxf(sred[2], sred[3]));
    float lsum = 0.f;
    #pragma unroll
    for (int jj = 0; jj < 8; ++jj) { x[jj] = __expf(x[jj] - gmax); lsum += x[jj]; }
    #pragma unroll
    for (int off = 1; off < 64; off <<= 1) lsum += __shfl_xor(lsum, off);
    if (l == 0) sred[4 + wv] = lsum;
    __syncthreads();
    float inv = 1.f / (sred[4] + sred[5] + sred[6] + sred[7]);
    #pragma unroll
    for (int jj = 0; jj < 8; ++jj) {
        int s = tid + jj * 256;
        wout[(size_t)b * S_ + s] = x[jj] * inv;
    }
}

// ---------- K4: tpart[ss][b][h] = sum_{s in slice ss} w[b,s] * sent_h[b,s,h] ----------
__global__ void k_wsum(const float* __restrict__ sent, const float* __restrict__ wrow_g,
                       float* __restrict__ tpart) {
    int b  = blockIdx.x >> 4;
    int ss = blockIdx.x & 15;
    int tid = threadIdx.x;
    __shared__ float wrow[128];
    if (tid < 128) wrow[tid] = wrow_g[(size_t)b * S_ + ss * 128 + tid];
    __syncthreads();
    const float* bp = sent + ((size_t)b * S_ + (size_t)ss * 128) * H_ + tid * 2;
    float ax = 0.f, ay = 0.f;
    for (int r0 = 0; r0 < 128; r0 += 8) {
        float2 v[8];
        #pragma unroll
        for (int u = 0; u < 8; ++u)
            v[u] = *(const float2*)(bp + (size_t)(r0 + u) * H_);
        #pragma unroll
        for (int u = 0; u < 8; ++u) {
            float wgt = wrow[r0 + u];
            ax = fmaf(wgt, v[u].x, ax);
            ay = fmaf(wgt, v[u].y, ay);
        }
    }
    float* tp = tpart + ((size_t)ss * B_ + b) * H_ + tid * 2;
    tp[0] = ax; tp[1] = ay;
}

// ---------- K5: att_res[b,h] = Wh_b[h] + sum_h' (sum_ss tpart[ss][b][h']) * Wh_w[h,h'] ----------
__global__ void k_att(const float* __restrict__ tpart, const float* __restrict__ Whw,
                      const float* __restrict__ Whb, float* __restrict__ out) {
    int tid = threadIdx.x;
    int b = blockIdx.x >> 2, q = blockIdx.x & 3;
    __shared__ __attribute__((aligned(16))) float st[H_];
    __shared__ float accs[128];
    for (int i = tid; i < H_; i += 256) {
        float s = 0.f;
        #pragma unroll
        for (int ss = 0; ss < 16; ++ss)
            s += tpart[((size_t)ss * B_ + b) * H_ + i];
        st[i] = s;
    }
    __syncthreads();
    int hh = tid & 127, half = tid >> 7;
    int h = q * 128 + hh;
    const float4* wr = (const float4*)(Whw + (size_t)h * H_) + half * 64;
    const float4* sx = (const float4*)st + half * 64;
    float acc = 0.f;
    #pragma unroll 8
    for (int i = 0; i < 64; ++i) {
        float4 w = wr[i]; float4 x = sx[i];
        acc += w.x * x.x + w.y * x.y + w.z * x.z + w.w * x.w;
    }
    if (half) accs[hh] = acc;
    __syncthreads();
    if (!half) out[(size_t)b * H_ + h] = acc + accs[hh] + Whb[h];
}

extern "C" void kernel_launch(void* const* d_in, const int* in_sizes, int n_in,
                              void* d_out, int out_size, void* d_ws, size_t ws_size,
                              hipStream_t stream) {
    const float* sent_h  = (const float*)d_in[0];
    const float* rel     = (const float*)d_in[1];
    const float* pool    = (const float*)d_in[2];
    const int*   mask    = (const int*)d_in[3];
    const float* Wg_w    = (const float*)d_in[4];
    const float* Wg_b    = (const float*)d_in[5];
    const float* Wh_w    = (const float*)d_in[6];
    const float* Wh_b    = (const float*)d_in[7];
    const float* Wr_w    = (const float*)d_in[8];
    const float* Wr_b    = (const float*)d_in[9];
    const float* alpha_w = (const float*)d_in[10];
    const float* alpha_b = (const float*)d_in[11];
    float* out = (float*)d_out;

    char* ws = (char*)d_ws;
    u16*   whwb    = (u16*)ws;                       // 524288 B
    float* base    = (float*)(ws + 524288);          // 131072 B
    float* partial = (float*)(ws + 524288 + 131072); // 2097152 B
    float* tpart   = (float*)(ws + 524288 + 131072 + 2097152); // 2097152 B

    float* att_out = out;             // [64,512]
    float* w_out   = out + B_ * H_;   // [64,2048]

    k_base<<<dim3(256), dim3(256), 0, stream>>>(rel, pool, Wg_w, Wg_b, Wh_b, Wr_w, Wr_b, Wh_w, base, whwb);
    k_gemm<<<dim3((M_ / 128) * 4), dim3(256), 0, stream>>>(sent_h, whwb, base, alpha_w, partial);
    k_softmax<<<dim3(B_), dim3(256), 0, stream>>>(partial, mask, alpha_b, w_out);
    k_wsum<<<dim3(B_ * 16), dim3(256), 0, stream>>>(sent_h, w_out, tpart);
    k_att<<<dim3(256), dim3(256), 0, stream>>>(tpart, Wh_w, Wh_b, att_out);
}